// Round 1
// 270.840 us; speedup vs baseline: 1.1974x; 1.1974x over previous
//
#include <hip/hip_runtime.h>
#include <cstdint>
#include <cstddef>

#define NNODES 50000
#define NEDGES 800000
#define INDIM  256
#define HD     128   // H*D
#define NH     4
#define NEG    0.2f

#define SCAN_B ((NNODES + 255) / 256)   // 196 blocks

// fusedA block partition
#define CONVH_BLKS (NNODES * INDIM / 8 / 256)       // 6250
#define HIST_BLKS  ((NEDGES + 255) / 256)           // 3125
#define CONVW_BLKS 64
// fusedB block partition
#define GEMM_BLKS  (2 * ((NNODES + 127) / 128))     // 782
#define SCAT_BLKS  ((NEDGES + 255) / 256)           // 3125

typedef __attribute__((ext_vector_type(8))) short   short8;   // 8 bf16 (4 VGPRs)
typedef __attribute__((ext_vector_type(8))) ushort  ushort8;
typedef __attribute__((ext_vector_type(4))) float   floatx4;

// f32 -> bf16 (round-to-nearest-even), raw bits
__device__ __forceinline__ ushort f2bf(float f) {
    unsigned u = __float_as_uint(f);
    unsigned r = u + 0x7fffu + ((u >> 16) & 1u);
    return (ushort)(r >> 16);
}
__device__ __forceinline__ float bf2f(ushort u) {
    return __uint_as_float(((unsigned)u) << 16);
}

// LDS chunk swizzle: conflict-free staging writes + fragment reads
__device__ __forceinline__ int swz(int c) { return c ^ ((c >> 4) & 7); }

// ================= fusedA: conv_h | hist | conv_w  (all independent) =================
__global__ __launch_bounds__(256) void fusedA_kernel(
        const float* __restrict__ h, ushort* __restrict__ h_bf,
        const int* __restrict__ dst, int* __restrict__ cnt_work,
        const float* __restrict__ Wsrc, const float* __restrict__ Wdst,
        ushort* __restrict__ Wt) {
    __shared__ float t[32][33];
    const int bid = blockIdx.x;
    const int tid = threadIdx.x;

    if (bid < CONVH_BLKS) {
        // ---- h convert: f32 -> bf16, 8 elems/thread ----
        int idx = bid * 256 + tid;                    // chunk of 8
        const int total = NNODES * INDIM / 8;         // 1.6M
        if (idx >= total) return;
        const float* p = h + (size_t)idx * 8;
        float4 v0 = *(const float4*)p;
        float4 v1 = *(const float4*)(p + 4);
        ushort8 o;
        o[0] = f2bf(v0.x); o[1] = f2bf(v0.y); o[2] = f2bf(v0.z); o[3] = f2bf(v0.w);
        o[4] = f2bf(v1.x); o[5] = f2bf(v1.y); o[6] = f2bf(v1.z); o[7] = f2bf(v1.w);
        *(ushort8*)(h_bf + (size_t)idx * 8) = o;
    } else if (bid < CONVH_BLKS + HIST_BLKS) {
        // ---- histogram of dst ----
        int e = (bid - CONVH_BLKS) * 256 + tid;
        if (e < NEDGES) atomicAdd(cnt_work + dst[e], 1);
    } else {
        // ---- W convert+transpose (LDS-tiled): Wt[n][k] bf16 ----
        int wb = bid - (CONVH_BLKS + HIST_BLKS);      // 0..63
        int kb = (wb & 7) * 32, nb = (wb >> 3) * 32;
        int tx = tid & 31, ty = tid >> 5;
        for (int i = ty; i < 32; i += 8) {
            int k = kb + i, n = nb + tx;
            float v = (n < HD) ? Wsrc[(size_t)k * HD + n] : Wdst[(size_t)k * HD + (n - HD)];
            t[i][tx] = v;
        }
        __syncthreads();
        for (int i = ty; i < 32; i += 8) {
            int n = nb + i, k = kb + tx;
            Wt[(size_t)n * INDIM + k] = f2bf(t[tx][i]);
        }
    }
}

// ================= CSR scans (unchanged) =================
__global__ __launch_bounds__(256) void scan_partial_kernel(
        const int* __restrict__ cnt, int* __restrict__ partials) {
    __shared__ int lds[256];
    int i = blockIdx.x * 256 + threadIdx.x;
    lds[threadIdx.x] = (i < NNODES) ? cnt[i] : 0;
    __syncthreads();
    for (int off = 128; off > 0; off >>= 1) {
        if (threadIdx.x < off) lds[threadIdx.x] += lds[threadIdx.x + off];
        __syncthreads();
    }
    if (threadIdx.x == 0) partials[blockIdx.x] = lds[0];
}

__global__ __launch_bounds__(256) void scan_offsets_kernel(
        int* __restrict__ partials, int* __restrict__ rowptr) {
    __shared__ int lds[256];
    int t = threadIdx.x;
    int v = (t < SCAN_B) ? partials[t] : 0;
    lds[t] = v;
    __syncthreads();
    for (int off = 1; off < 256; off <<= 1) {
        int u = (t >= off) ? lds[t - off] : 0;
        __syncthreads();
        lds[t] += u;
        __syncthreads();
    }
    if (t < SCAN_B) partials[t] = lds[t] - v;      // exclusive
    if (t == 255) rowptr[NNODES] = lds[255];       // total
}

__global__ __launch_bounds__(256) void scan_final_kernel(
        int* __restrict__ cnt_work, const int* __restrict__ partials,
        int* __restrict__ rowptr) {
    __shared__ int lds[256];
    int i = blockIdx.x * 256 + threadIdx.x;
    int t = threadIdx.x;
    int v = (i < NNODES) ? cnt_work[i] : 0;
    lds[t] = v;
    __syncthreads();
    for (int off = 1; off < 256; off <<= 1) {
        int u = (t >= off) ? lds[t - off] : 0;
        __syncthreads();
        lds[t] += u;
        __syncthreads();
    }
    if (i < NNODES) {
        int start = partials[blockIdx.x] + lds[t] - v;
        rowptr[i] = start;
        cnt_work[i] = start;
    }
}

// ================= fusedB: MFMA GEMM | scatter  (both ready after scans+fusedA) =====
__global__ __launch_bounds__(256) void fusedB_kernel(
        const ushort* __restrict__ h_bf, const ushort* __restrict__ Wt,
        const float* __restrict__ bsrc, const float* __restrict__ bdst,
        ushort* __restrict__ el_bf, float* __restrict__ er,
        const int* __restrict__ src, const int* __restrict__ dst,
        int* __restrict__ cnt_work,
        int* __restrict__ eidx, int* __restrict__ esrc) {
    __shared__ ushort As[512 * 8];  // 512 fragment-chunks of 8 bf16
    __shared__ ushort Bs[512 * 8];

    const int bid = blockIdx.x;
    const int tid = threadIdx.x;

    if (bid >= GEMM_BLKS) {
        // ---- scatter: build CSR edge lists ----
        int e = (bid - GEMM_BLKS) * 256 + tid;
        if (e >= NEDGES) return;
        int s = src[e];
        int pos = atomicAdd(cnt_work + dst[e], 1);
        eidx[pos] = e;
        esrc[pos] = s;
        return;
    }

    // ---- GEMM: bx==0 -> el (bf16 out), bx==1 -> er (f32 out). 128x128 per block ----
    const int bx = bid & 1, by = bid >> 1;
    const int wave = tid >> 6, lane = tid & 63;
    const int row0 = by * 128;
    const int col0 = bx * 128;   // 0 -> el, 128 -> er
    const int l15  = lane & 15, quad = lane >> 4;

    floatx4 acc[2][8];
#pragma unroll
    for (int i = 0; i < 2; ++i)
#pragma unroll
        for (int j = 0; j < 8; ++j) acc[i][j] = (floatx4){0.f, 0.f, 0.f, 0.f};

    for (int kk = 0; kk < INDIM; kk += 32) {
#pragma unroll
        for (int it = 0; it < 2; ++it) {
            int idx = tid + it * 256;    // 0..511
            int r = idx >> 2;            // 0..127
            int kq = idx & 3;            // k-quad (8 elems)
            int c = (r >> 4) * 64 + kq * 16 + (r & 15);
            // ---- A: pre-converted bf16 ----
            int grow = row0 + r;
            ushort8 aw = (ushort8){0,0,0,0,0,0,0,0};
            if (grow < NNODES)
                aw = *(const ushort8*)(h_bf + (size_t)grow * INDIM + kk + kq * 8);
            *(ushort8*)(As + swz(c) * 8) = aw;
            // ---- B ----
            ushort8 bw = *(const ushort8*)(Wt + (size_t)(col0 + r) * INDIM + kk + kq * 8);
            *(ushort8*)(Bs + swz(c) * 8) = bw;
        }
        __syncthreads();

        short8 af[2], bf[8];
#pragma unroll
        for (int tm = 0; tm < 2; ++tm) {
            int c = (wave * 2 + tm) * 64 + quad * 16 + l15;
            af[tm] = *(const short8*)(As + swz(c) * 8);
        }
#pragma unroll
        for (int tn = 0; tn < 8; ++tn) {
            int c = tn * 64 + quad * 16 + l15;
            bf[tn] = *(const short8*)(Bs + swz(c) * 8);
        }
#pragma unroll
        for (int tm = 0; tm < 2; ++tm)
#pragma unroll
            for (int tn = 0; tn < 8; ++tn)
                acc[tm][tn] = __builtin_amdgcn_mfma_f32_16x16x32_bf16(
                    af[tm], bf[tn], acc[tm][tn], 0, 0, 0);
        __syncthreads();
    }

    // epilogue: C/D layout col=lane&15, row=quad*4+reg
    if (col0 == 0) {
#pragma unroll
        for (int tn = 0; tn < 8; ++tn) {
            int col = tn * 16 + l15;
            float bias = bsrc[col];
#pragma unroll
            for (int tm = 0; tm < 2; ++tm)
#pragma unroll
                for (int reg = 0; reg < 4; ++reg) {
                    int row = row0 + wave * 32 + tm * 16 + quad * 4 + reg;
                    if (row < NNODES)
                        el_bf[(size_t)row * HD + col] = f2bf(acc[tm][tn][reg] + bias);
                }
        }
    } else {
#pragma unroll
        for (int tn = 0; tn < 8; ++tn) {
            int col = tn * 16 + l15;
            float bias = bdst[col];
#pragma unroll
            for (int tm = 0; tm < 2; ++tm)
#pragma unroll
                for (int reg = 0; reg < 4; ++reg) {
                    int row = row0 + wave * 32 + tm * 16 + quad * 4 + reg;
                    if (row < NNODES)
                        er[(size_t)row * HD + col] = acc[tm][tn][reg] + bias;
                }
        }
    }
}

// ================= fused: scores + online softmax + aggregate + normalize =================
// one wave per node; lane l owns dims 2l,2l+1; head hh = l>>4.
// Batched-gather restructure: indices preloaded 16 at a time (coalesced), broadcast
// via readlane into SGPRs -> scalar-base gathers, 16 loads in flight, no per-edge
// dependent esrc->el chain. Raw scores stashed in LDS (cap 128 edges/node);
// deg>128 falls back to a recompute path (never taken at mean degree 16, but correct).
#define DEGCAP 128

__global__ __launch_bounds__(256) void node_fused_kernel(
        const ushort* __restrict__ el_bf, const float* __restrict__ er,
        const int* __restrict__ rowptr, const int* __restrict__ eidx,
        const int* __restrict__ esrc,
        const float* __restrict__ attn,
        float* __restrict__ out_feat, float* __restrict__ out_a) {
    __shared__ float sp[4][DEGCAP * NH];   // 2 KB per wave

    const int wv = threadIdx.x >> 6;
    const int n = blockIdx.x * 4 + wv;
    if (n >= NNODES) return;
    const int lane = threadIdx.x & 63;
    const int hh = lane >> 4;
    const int lo = rowptr[n], hi = rowptr[n + 1];
    const int deg = hi - lo;
    float* spw = sp[wv];
    const int l2 = lane * 2;

    const float2 rv = *(const float2*)(er + (size_t)n * HD + l2);
    const float a0 = attn[l2], a1 = attn[l2 + 1];

    float m = -3.4e38f, lsum = 0.0f, acc0 = 0.0f, acc1 = 0.0f;

    if (deg > 0 && deg <= DEGCAP) {
        // preload first chunk of up to 16 edge-source indices (coalesced, clamped)
        int jj0 = (lane & 15);
        if (jj0 >= deg) jj0 = deg - 1;
        int si = esrc[lo + jj0];

        for (int base = 0; base < deg; base += 16) {
            // issue all gathers of this chunk (wave-uniform scalar base per edge)
            ushort2 u[16];
#pragma unroll
            for (int j = 0; j < 16; ++j) {
                if (base + j < deg) {
                    int s = __builtin_amdgcn_readlane(si, j);
                    u[j] = *(const ushort2*)(el_bf + (size_t)s * HD + l2);
                }
            }
            // prefetch next chunk's indices (hides index-load latency under compute)
            int si_nxt = si;
            if (base + 16 < deg) {
                int jj = base + 16 + (lane & 15);
                if (jj >= deg) jj = deg - 1;
                si_nxt = esrc[lo + jj];
            }
            // process chunk
#pragma unroll
            for (int j = 0; j < 16; ++j) {
                if (base + j < deg) {
                    float evx = bf2f(u[j].x), evy = bf2f(u[j].y);
                    float x0 = evx + rv.x; x0 = x0 > 0.f ? x0 : NEG * x0;
                    float x1 = evy + rv.y; x1 = x1 > 0.f ? x1 : NEG * x1;
                    float p = x0 * a0 + x1 * a1;
                    p += __shfl_xor(p, 1, 16);
                    p += __shfl_xor(p, 2, 16);
                    p += __shfl_xor(p, 4, 16);
                    p += __shfl_xor(p, 8, 16);
                    if ((lane & 15) == 0) spw[(base + j) * NH + hh] = p;
                    float mn = fmaxf(m, p);
                    float sc = __expf(m - mn);
                    float w  = __expf(p - mn);
                    lsum = lsum * sc + w;
                    acc0 = acc0 * sc + w * evx;
                    acc1 = acc1 * sc + w * evy;
                    m = mn;
                }
            }
            si = si_nxt;
        }
    } else if (deg > DEGCAP) {
        // fallback pass 1: online softmax only (no score stash)
        ushort2 u = {0,0};
        { int s_ = esrc[lo]; u = *(const ushort2*)(el_bf + (size_t)s_ * HD + l2); }
        for (int i = lo; i < hi; ++i) {
            float evx = bf2f(u.x), evy = bf2f(u.y);
            if (i + 1 < hi) { int s_ = esrc[i + 1];
                u = *(const ushort2*)(el_bf + (size_t)s_ * HD + l2); }
            float x0 = evx + rv.x; x0 = x0 > 0.f ? x0 : NEG * x0;
            float x1 = evy + rv.y; x1 = x1 > 0.f ? x1 : NEG * x1;
            float p = x0 * a0 + x1 * a1;
            p += __shfl_xor(p, 1, 16);
            p += __shfl_xor(p, 2, 16);
            p += __shfl_xor(p, 4, 16);
            p += __shfl_xor(p, 8, 16);
            float mn = fmaxf(m, p);
            float sc = __expf(m - mn);
            float w  = __expf(p - mn);
            lsum = lsum * sc + w;
            acc0 = acc0 * sc + w * evx;
            acc1 = acc1 * sc + w * evy;
            m = mn;
        }
    }

    // write aggregated features
    float2 o;
    if (deg == 0) { o.x = 0.0f; o.y = 0.0f; }
    else { float inv = 1.0f / lsum; o.x = acc0 * inv; o.y = acc1 * inv; }
    *(float2*)(out_feat + (size_t)n * HD + l2) = o;

    if (deg == 0) return;

    // normalize + write attention weights
    float inv = 1.0f / lsum;
    if (deg <= DEGCAP) {
        // broadcast (m, inv) of head (lane&3) from its group (values uniform in group)
        float mh   = __shfl(m,   (lane & 3) << 4, 64);
        float invh = __shfl(inv, (lane & 3) << 4, 64);
        for (int j = (lane >> 2); j < deg; j += 16) {
            int e = eidx[lo + j];
            float p = spw[j * NH + (lane & 3)];
            out_a[(size_t)e * NH + (lane & 3)] = __expf(p - mh) * invh;
        }
    } else {
        // fallback pass 2: recompute scores and write a
        for (int i = lo; i < hi; ++i) {
            int s_ = esrc[i];
            ushort2 u = *(const ushort2*)(el_bf + (size_t)s_ * HD + l2);
            float evx = bf2f(u.x), evy = bf2f(u.y);
            float x0 = evx + rv.x; x0 = x0 > 0.f ? x0 : NEG * x0;
            float x1 = evy + rv.y; x1 = x1 > 0.f ? x1 : NEG * x1;
            float p = x0 * a0 + x1 * a1;
            p += __shfl_xor(p, 1, 16);
            p += __shfl_xor(p, 2, 16);
            p += __shfl_xor(p, 4, 16);
            p += __shfl_xor(p, 8, 16);
            if ((lane & 15) == 0) {
                int e = eidx[i];
                out_a[(size_t)e * NH + hh] = __expf(p - m) * inv;
            }
        }
    }
}

extern "C" void kernel_launch(void* const* d_in, const int* in_sizes, int n_in,
                              void* d_out, int out_size, void* d_ws, size_t ws_size,
                              hipStream_t stream) {
    const float* h    = (const float*)d_in[0];
    const int*   src  = (const int*)d_in[1];
    const int*   dst  = (const int*)d_in[2];
    const float* Wsrc = (const float*)d_in[3];
    const float* bsrc = (const float*)d_in[4];
    const float* Wdst = (const float*)d_in[5];
    const float* bdst = (const float*)d_in[6];
    const float* attn = (const float*)d_in[7];

    float* out_feat = (float*)d_out;                       // N*128
    float* out_a    = out_feat + (size_t)NNODES * HD;      // E*4

    // h_bf scratch lives in d_out (38.4 MB region, fully rewritten later):
    // fusedA -> fusedB consume it before node_fused overwrites the region.
    ushort* h_bf = (ushort*)d_out;                         // N*256 bf16 = 25.6 MB

    // workspace layout (16B-aligned chunks)
    float*  er       = (float*)d_ws;                         // N*128 f32
    ushort* Wt       = (ushort*)(er + (size_t)NNODES * HD);  // 256*256 bf16
    ushort* el_bf    = Wt + 2 * HD * INDIM;                  // N*128 bf16
    int*    cnt_work = (int*)(el_bf + (size_t)NNODES * HD);  // N
    int*    eidx     = cnt_work + NNODES;                    // E
    int*    esrc     = eidx + NEDGES;                        // E
    int*    rowptr   = esrc + NEDGES;                        // N+1
    int*    partials = rowptr + NNODES + 1;                  // SCAN_B

    hipMemsetAsync(cnt_work, 0, NNODES * sizeof(int), stream);

    // fusedA: h->bf16 convert | dst histogram | W convert+transpose (independent)
    fusedA_kernel<<<CONVH_BLKS + HIST_BLKS + CONVW_BLKS, 256, 0, stream>>>(
        h, h_bf, dst, cnt_work, Wsrc, Wdst, Wt);

    // CSR prefix-sum chain
    scan_partial_kernel<<<SCAN_B, 256, 0, stream>>>(cnt_work, partials);
    scan_offsets_kernel<<<1, 256, 0, stream>>>(partials, rowptr);
    scan_final_kernel<<<SCAN_B, 256, 0, stream>>>(cnt_work, partials, rowptr);

    // fusedB: MFMA GEMM (el, er) | CSR scatter (independent at this point)
    fusedB_kernel<<<GEMM_BLKS + SCAT_BLKS, 256, 0, stream>>>(
        h_bf, Wt, bsrc, bdst, el_bf, er, src, dst, cnt_work, eidx, esrc);

    node_fused_kernel<<<(NNODES + 3) / 4, 256, 0, stream>>>(
        el_bf, er, rowptr, eidx, esrc, attn, out_feat, out_a);
}